// Round 1
// baseline (975.566 us; speedup 1.0000x reference)
//
#include <hip/hip_runtime.h>
#include <math.h>

namespace {

constexpr int HW    = 56 * 56;       // 3136
constexpr int NB    = 64;
constexpr int CTOT  = 256;
constexpr int CPG   = 16;            // channels per group
constexpr int GRP   = 16;
constexpr int MTOT  = NB * HW;       // 200704 positions per channel
constexpr int NPAIR = 136;           // upper triangle incl. diagonal of 16x16
constexpr int NACC  = CPG + NPAIR;   // 152 accumulators per group
constexpr float EPSR = 1e-4f;
constexpr int BPG1  = 32;            // blocks per group, stats pass
constexpr int BPG3  = 64;            // blocks per group, apply pass
constexpr int NS_IT = 14;            // Newton-Schulz iterations (converges ~8 for cov≈I)

__host__ __device__ constexpr int pair_idx(int i, int j) {
    // i <= j, row-major packed upper triangle
    return i * CPG - (i * (i - 1)) / 2 + (j - i);
}

// ---------------- Pass 1: per-group channel sums + cross-product sums ----------------
// cov[g][i][j] = (sum x_i x_j)/M - mu_i mu_j  -> only need raw sums in ONE read of x.
__global__ __launch_bounds__(256, 2)
void cov_kernel(const float* __restrict__ x, float* __restrict__ accg) {
    const int g   = blockIdx.x / BPG1;
    const int b   = blockIdx.x % BPG1;
    const int tid = threadIdx.x;

    float sum[CPG];
    float acc[NPAIR];
#pragma unroll
    for (int i = 0; i < CPG; ++i) sum[i] = 0.f;
#pragma unroll
    for (int k = 0; k < NPAIR; ++k) acc[k] = 0.f;

    const int stride = BPG1 * 256;
    for (int m = b * 256 + tid; m < MTOT; m += stride) {
        const int n  = m / HW;
        const int hw = m - n * HW;
        const float* p = x + (size_t)(n * CTOT + g * CPG) * HW + hw;
        float v[CPG];
#pragma unroll
        for (int j = 0; j < CPG; ++j) v[j] = p[(size_t)j * HW];  // coalesced per j
#pragma unroll
        for (int i = 0; i < CPG; ++i) {
            sum[i] += v[i];
#pragma unroll
            for (int j = i; j < CPG; ++j)
                acc[pair_idx(i, j)] += v[i] * v[j];
        }
    }

    // wave-level butterfly reduction (every lane ends with the wave total)
#pragma unroll
    for (int i = 0; i < CPG; ++i) {
#pragma unroll
        for (int s = 32; s > 0; s >>= 1) sum[i] += __shfl_xor(sum[i], s, 64);
    }
#pragma unroll
    for (int k = 0; k < NPAIR; ++k) {
#pragma unroll
        for (int s = 32; s > 0; s >>= 1) acc[k] += __shfl_xor(acc[k], s, 64);
    }

    __shared__ float red[4][NACC];
    const int wave = tid >> 6;
    const int lane = tid & 63;
    if (lane == 0) {
#pragma unroll
        for (int i = 0; i < CPG; ++i) red[wave][i] = sum[i];
#pragma unroll
        for (int k = 0; k < NPAIR; ++k) red[wave][CPG + k] = acc[k];
    }
    __syncthreads();
    if (tid < NACC) {
        const float v = red[0][tid] + red[1][tid] + red[2][tid] + red[3][tid];
        atomicAdd(&accg[g * NACC + tid], v);
    }
}

// ---------------- Pass 2: Newton-Schulz inverse sqrt of 16 16x16 covariances ----------------
// Coupled iteration: T = 1.5I - 0.5*Z*Y; Y <- Y*T; Z <- T*Z.  Z -> (A/tr)^{-1/2},
// so P = Z / sqrt(tr) = (cov + eps I)^{-1/2}  (identical to eigh-based proj).
__global__ __launch_bounds__(256, 1)
void ns_kernel(const float* __restrict__ accg,
               float* __restrict__ Pout, float* __restrict__ shiftout) {
    __shared__ float A[CPG][CPG], Y[CPG][CPG], Z[CPG][CPG], T[CPG][CPG];
    __shared__ float mu[CPG];
    __shared__ float s_tr;
    const int g = blockIdx.x;
    const int t = threadIdx.x;
    const int i = t >> 4, j = t & 15;
    const float* a = accg + g * NACC;
    const float invM = 1.0f / (float)MTOT;

    if (t < CPG) mu[t] = a[t] * invM;
    __syncthreads();
    {
        const int lo = i < j ? i : j;
        const int hi = i < j ? j : i;
        float c = a[CPG + pair_idx(lo, hi)] * invM - mu[i] * mu[j];
        if (i == j) c += EPSR;
        A[i][j] = c;
    }
    __syncthreads();
    if (t == 0) {
        float tr = 0.f;
        for (int k = 0; k < CPG; ++k) tr += A[k][k];
        s_tr = tr;
    }
    __syncthreads();
    const float tr = s_tr;
    Y[i][j] = A[i][j] / tr;
    Z[i][j] = (i == j) ? 1.f : 0.f;
    __syncthreads();

    for (int it = 0; it < NS_IT; ++it) {
        float zy = 0.f;
#pragma unroll
        for (int k = 0; k < CPG; ++k) zy += Z[i][k] * Y[k][j];
        const float tij = ((i == j) ? 1.5f : 0.f) - 0.5f * zy;
        T[i][j] = tij;
        __syncthreads();
        float y2 = 0.f, z2 = 0.f;
#pragma unroll
        for (int k = 0; k < CPG; ++k) {
            y2 += Y[i][k] * T[k][j];
            z2 += T[i][k] * Z[k][j];
        }
        __syncthreads();
        Y[i][j] = y2;
        Z[i][j] = z2;
        __syncthreads();
    }

    const float p = Z[i][j] / sqrtf(tr);
    Pout[g * 256 + t] = p;

    // shift[i] = sum_j P[i][j] * mu[j]  (so apply pass does w*(P·x - shift) + b)
    T[i][j] = p;
    __syncthreads();
    if (t < CPG) {
        float o = 0.f;
        for (int k = 0; k < CPG; ++k) o += T[t][k] * mu[k];
        shiftout[g * CPG + t] = o;
    }
}

// ---------------- Pass 3: apply whitening, scale, bias ----------------
// Each thread handles 4 consecutive positions (float4); 16 in / 16 out channels.
// HW % 4 == 0 so a float4 never crosses the n-boundary.
__global__ __launch_bounds__(256, 2)
void apply_kernel(const float* __restrict__ x, const float* __restrict__ Pg,
                  const float* __restrict__ shiftg,
                  const float* __restrict__ weight, const float* __restrict__ bias,
                  float* __restrict__ out) {
    const int g = blockIdx.x / BPG3;
    const int b = blockIdx.x % BPG3;
    const int t = threadIdx.x;
    __shared__ float P[CPG][CPG];
    __shared__ float wv[CPG], bv[CPG];

    P[t >> 4][t & 15] = Pg[g * 256 + t];
    if (t < CPG) {
        const int c = g * CPG + t;
        const float w = weight[c];
        wv[t] = w;
        bv[t] = bias[c] - w * shiftg[g * CPG + t];
    }
    __syncthreads();

    const int nchunk = MTOT / 4;       // 50176 float4-chunks per group
    const int stride = BPG3 * 256;
    for (int ch = b * 256 + t; ch < nchunk; ch += stride) {
        const int m  = ch * 4;
        const int n  = m / HW;
        const int hw = m - n * HW;
        const float* px = x + (size_t)(n * CTOT + g * CPG) * HW + hw;
        float4 v[CPG];
#pragma unroll
        for (int j = 0; j < CPG; ++j)
            v[j] = *(const float4*)(px + (size_t)j * HW);
        float* po = out + (size_t)(n * CTOT + g * CPG) * HW + hw;
#pragma unroll
        for (int i = 0; i < CPG; ++i) {
            float4 y = make_float4(0.f, 0.f, 0.f, 0.f);
#pragma unroll
            for (int j = 0; j < CPG; ++j) {
                const float pij = P[i][j];     // LDS broadcast, amortized over 4 positions
                y.x += pij * v[j].x;
                y.y += pij * v[j].y;
                y.z += pij * v[j].z;
                y.w += pij * v[j].w;
            }
            const float w = wv[i], bb = bv[i];
            float4 r;
            r.x = fmaf(w, y.x, bb);
            r.y = fmaf(w, y.y, bb);
            r.z = fmaf(w, y.z, bb);
            r.w = fmaf(w, y.w, bb);
            *(float4*)(po + (size_t)i * HW) = r;
        }
    }
}

} // namespace

extern "C" void kernel_launch(void* const* d_in, const int* in_sizes, int n_in,
                              void* d_out, int out_size, void* d_ws, size_t ws_size,
                              hipStream_t stream) {
    const float* x      = (const float*)d_in[0];
    const float* weight = (const float*)d_in[1];
    const float* bias   = (const float*)d_in[2];
    float* out = (float*)d_out;
    float* ws  = (float*)d_ws;

    float* acc   = ws;            // 16 * 152 floats
    float* P     = ws + 2560;     // 16 * 256 floats
    float* shift = ws + 6656;     // 16 * 16 floats

    // ws is poisoned 0xAA before every launch -> zero the atomic accumulators.
    hipMemsetAsync(acc, 0, GRP * NACC * sizeof(float), stream);

    cov_kernel<<<GRP * BPG1, 256, 0, stream>>>(x, acc);
    ns_kernel<<<GRP, 256, 0, stream>>>(acc, P, shift);
    apply_kernel<<<GRP * BPG3, 256, 0, stream>>>(x, P, shift, weight, bias, out);
}

// Round 2
// 795.090 us; speedup vs baseline: 1.2270x; 1.2270x over previous
//
#include <hip/hip_runtime.h>
#include <math.h>

namespace {

constexpr int HW    = 56 * 56;       // 3136
constexpr int NB    = 64;
constexpr int CTOT  = 256;
constexpr int CPG   = 16;            // channels per group
constexpr int GRP   = 16;
constexpr int MTOT  = NB * HW;       // 200704 positions per channel
constexpr int NPAIR = 136;           // upper triangle incl. diagonal of 16x16
constexpr int NACC  = CPG + NPAIR;   // 152 accumulators per group
constexpr float EPSR = 1e-4f;
constexpr int BPG1  = 32;            // blocks per group, stats pass (512 blocks = 2/CU)
constexpr int NS_IT = 14;            // Newton-Schulz iterations
constexpr int TPOS  = 1024;          // positions per apply tile (last tile/slab = 64)
constexpr int TPS   = 4;             // tiles per (n,g) slab: 3136 = 3*1024 + 64

__host__ __device__ constexpr int pair_idx(int i, int j) {
    return i * CPG - (i * (i - 1)) / 2 + (j - i);
}

#define AS_GLOBAL(p) ((const __attribute__((address_space(1))) void*)(p))
#define AS_LOCAL(p)  ((__attribute__((address_space(3))) void*)(p))

// ---------------- Pass 1: raw channel sums + cross-product sums (one read of x) ------
// Control experiment: direct float4 global->register loads (no LDS staging).
__global__ __launch_bounds__(256, 2)
void cov_kernel(const float* __restrict__ x, float* __restrict__ accg) {
    const int g   = blockIdx.x / BPG1;
    const int b   = blockIdx.x % BPG1;
    const int tid = threadIdx.x;

    float sum[CPG];
    float acc[NPAIR];
#pragma unroll
    for (int i = 0; i < CPG; ++i) sum[i] = 0.f;
#pragma unroll
    for (int k = 0; k < NPAIR; ++k) acc[k] = 0.f;

    const int nchunk = MTOT / 4;           // 50176 float4 chunks per channel
    const int stride = BPG1 * 256;         // 8192
    for (int ch = b * 256 + tid; ch < nchunk; ch += stride) {
        const int m  = ch * 4;
        const int n  = m / HW;
        const int hw = m - n * HW;         // float4 never crosses n-boundary (HW%4==0)
        const float* p = x + (size_t)(n * CTOT + g * CPG) * HW + hw;
        float4 v[CPG];
#pragma unroll
        for (int j = 0; j < CPG; ++j)
            v[j] = *(const float4*)(p + (size_t)j * HW);   // 1 KiB wave-run per j
#pragma unroll
        for (int i = 0; i < CPG; ++i)
            sum[i] += (v[i].x + v[i].y) + (v[i].z + v[i].w);
#pragma unroll
        for (int i = 0; i < CPG; ++i)
#pragma unroll
            for (int j = i; j < CPG; ++j) {
                const int k = pair_idx(i, j);
                acc[k] = fmaf(v[i].x, v[j].x, acc[k]);
                acc[k] = fmaf(v[i].y, v[j].y, acc[k]);
                acc[k] = fmaf(v[i].z, v[j].z, acc[k]);
                acc[k] = fmaf(v[i].w, v[j].w, acc[k]);
            }
    }

    // wave butterfly: every lane ends with the wave total
#pragma unroll
    for (int i = 0; i < CPG; ++i) {
#pragma unroll
        for (int s = 32; s > 0; s >>= 1) sum[i] += __shfl_xor(sum[i], s, 64);
    }
#pragma unroll
    for (int k = 0; k < NPAIR; ++k) {
#pragma unroll
        for (int s = 32; s > 0; s >>= 1) acc[k] += __shfl_xor(acc[k], s, 64);
    }

    __shared__ float red[4][NACC];
    const int wave = tid >> 6;
    const int lane = tid & 63;
    if (lane == 0) {
#pragma unroll
        for (int i = 0; i < CPG; ++i) red[wave][i] = sum[i];
#pragma unroll
        for (int k = 0; k < NPAIR; ++k) red[wave][CPG + k] = acc[k];
    }
    __syncthreads();
    if (tid < NACC) {
        const float v = red[0][tid] + red[1][tid] + red[2][tid] + red[3][tid];
        atomicAdd(&accg[g * NACC + tid], v);
    }
}

// ---------------- Pass 2: Newton-Schulz inverse sqrt; fold weight/bias/mean in -------
// Outputs: Pw[g][i][j] = w_i * (cov+eps I)^{-1/2}[i][j]
//          bf[g][i]    = bias_i - sum_j Pw[i][j] * mu[j]
__global__ __launch_bounds__(256, 1)
void ns_kernel(const float* __restrict__ accg,
               const float* __restrict__ weight, const float* __restrict__ bias,
               float* __restrict__ Pout, float* __restrict__ bfout) {
    __shared__ float A[CPG][CPG], Y[CPG][CPG], Z[CPG][CPG], T[CPG][CPG];
    __shared__ float mu[CPG];
    __shared__ float s_tr;
    const int g = blockIdx.x;
    const int t = threadIdx.x;
    const int i = t >> 4, j = t & 15;
    const float* a = accg + g * NACC;
    const float invM = 1.0f / (float)MTOT;

    if (t < CPG) mu[t] = a[t] * invM;
    __syncthreads();
    {
        const int lo = i < j ? i : j;
        const int hi = i < j ? j : i;
        float c = a[CPG + pair_idx(lo, hi)] * invM - mu[i] * mu[j];
        if (i == j) c += EPSR;
        A[i][j] = c;
    }
    __syncthreads();
    if (t == 0) {
        float tr = 0.f;
        for (int k = 0; k < CPG; ++k) tr += A[k][k];
        s_tr = tr;
    }
    __syncthreads();
    const float tr = s_tr;
    Y[i][j] = A[i][j] / tr;
    Z[i][j] = (i == j) ? 1.f : 0.f;
    __syncthreads();

    for (int it = 0; it < NS_IT; ++it) {
        float zy = 0.f;
#pragma unroll
        for (int k = 0; k < CPG; ++k) zy += Z[i][k] * Y[k][j];
        const float tij = ((i == j) ? 1.5f : 0.f) - 0.5f * zy;
        T[i][j] = tij;
        __syncthreads();
        float y2 = 0.f, z2 = 0.f;
#pragma unroll
        for (int k = 0; k < CPG; ++k) {
            y2 += Y[i][k] * T[k][j];
            z2 += T[i][k] * Z[k][j];
        }
        __syncthreads();
        Y[i][j] = y2;
        Z[i][j] = z2;
        __syncthreads();
    }

    const float pw = (Z[i][j] / sqrtf(tr)) * weight[g * CPG + i];
    Pout[g * 256 + t] = pw;

    T[i][j] = pw;
    __syncthreads();
    if (t < CPG) {
        float o = 0.f;
        for (int k = 0; k < CPG; ++k) o += T[t][k] * mu[k];
        bfout[g * CPG + t] = bias[g * CPG + t] - o;
    }
}

// ---------------- Pass 3: out = Pw . x + bf  (LDS-staged, wave-specialized) ----------
// Block owns one 1024-position tile of one (n,g) slab. Stage 16ch x 1024pos (64 KB)
// via async global_load_lds(16B); wave w computes output channels 4w..4w+3.
__global__ __launch_bounds__(256, 2)
void apply_kernel(const float* __restrict__ x, const float* __restrict__ Pg,
                  const float* __restrict__ bfg, float* __restrict__ out) {
    __shared__ __align__(16) float xs[CPG][TPOS];   // 64 KB
    __shared__ float Pl[CPG][CPG];

    const int bid  = blockIdx.x;
    const int tile = bid & (TPS - 1);
    const int slab = bid >> 2;
    const int g    = slab & (GRP - 1);
    const int n    = slab >> 4;
    const int t    = threadIdx.x;
    const int lane = t & 63;
    const int w    = t >> 6;

    const int pos0 = tile * TPOS;
    const int npos = min(TPOS, HW - pos0);          // 1024 or 64
    const float* xbase = x + ((size_t)n * CTOT + g * CPG) * HW + pos0;

    Pl[t >> 4][t & 15] = Pg[g * 256 + t];

    // async stage: wave w loads channels 4w..4w+3; 16 B/lane, 1 KiB/instruction
#pragma unroll
    for (int jj = 0; jj < 4; ++jj) {
        const int j = w * 4 + jj;
        const float* src = xbase + (size_t)j * HW;
#pragma unroll
        for (int q = 0; q < 4; ++q) {
            const int f = q * 64 + lane;
            if (4 * f < npos) {
                __builtin_amdgcn_global_load_lds(AS_GLOBAL(src + 4 * f),
                                                 AS_LOCAL(&xs[j][q * 256]),
                                                 16, 0, 0);
            }
        }
    }
    __syncthreads();

    const int i0 = w * 4;
    float4 acc[4][4];                               // [out-channel][q]
#pragma unroll
    for (int ii = 0; ii < 4; ++ii)
#pragma unroll
        for (int q = 0; q < 4; ++q) acc[ii][q] = make_float4(0.f, 0.f, 0.f, 0.f);

#pragma unroll
    for (int j = 0; j < CPG; ++j) {
        float4 xv[4];
#pragma unroll
        for (int q = 0; q < 4; ++q)
            xv[q] = *(const float4*)&xs[j][4 * (q * 64 + lane)];
        float p[4];
#pragma unroll
        for (int ii = 0; ii < 4; ++ii) p[ii] = Pl[i0 + ii][j];   // wave-uniform broadcast
#pragma unroll
        for (int ii = 0; ii < 4; ++ii)
#pragma unroll
            for (int q = 0; q < 4; ++q) {
                acc[ii][q].x = fmaf(p[ii], xv[q].x, acc[ii][q].x);
                acc[ii][q].y = fmaf(p[ii], xv[q].y, acc[ii][q].y);
                acc[ii][q].z = fmaf(p[ii], xv[q].z, acc[ii][q].z);
                acc[ii][q].w = fmaf(p[ii], xv[q].w, acc[ii][q].w);
            }
    }

#pragma unroll
    for (int ii = 0; ii < 4; ++ii) {
        const int i = i0 + ii;
        const float bb = bfg[g * CPG + i];          // wave-uniform scalar load
        float* po = out + ((size_t)n * CTOT + g * CPG + i) * HW + pos0;
#pragma unroll
        for (int q = 0; q < 4; ++q) {
            const int f = q * 64 + lane;
            if (4 * f < npos) {
                float4 r;
                r.x = acc[ii][q].x + bb;
                r.y = acc[ii][q].y + bb;
                r.z = acc[ii][q].z + bb;
                r.w = acc[ii][q].w + bb;
                *(float4*)(po + 4 * f) = r;
            }
        }
    }
}

} // namespace

extern "C" void kernel_launch(void* const* d_in, const int* in_sizes, int n_in,
                              void* d_out, int out_size, void* d_ws, size_t ws_size,
                              hipStream_t stream) {
    const float* x      = (const float*)d_in[0];
    const float* weight = (const float*)d_in[1];
    const float* bias   = (const float*)d_in[2];
    float* out = (float*)d_out;
    float* ws  = (float*)d_ws;

    float* acc = ws;            // 16 * 152 floats (padded region 2560)
    float* Pw  = ws + 2560;     // 16 * 256 floats
    float* bf  = ws + 6656;     // 16 * 16 floats

    hipMemsetAsync(acc, 0, GRP * NACC * sizeof(float), stream);

    cov_kernel<<<GRP * BPG1, 256, 0, stream>>>(x, acc);
    ns_kernel<<<GRP, 256, 0, stream>>>(acc, weight, bias, Pw, bf);
    apply_kernel<<<NB * GRP * TPS, 256, 0, stream>>>(x, Pw, bf, out);
}